// Round 5
// baseline (3031.180 us; speedup 1.0000x reference)
//
#include <hip/hip_runtime.h>
#include <hip/hip_bf16.h>
#include <math.h>

typedef unsigned short ushort_t;
typedef __attribute__((ext_vector_type(8))) __bf16 bf16x8;
typedef __attribute__((ext_vector_type(4))) float f32x4;
typedef __attribute__((ext_vector_type(8))) short s8v;
typedef __attribute__((ext_vector_type(4))) short s4v;

#define SQ 2048
#define DM 1024
#define NH 16
#define HDIM 64
#define FFD 4096
#define NVOC 32000

__device__ inline float b2f(unsigned short u) {
  union { unsigned int i; float f; } x; x.i = ((unsigned int)u) << 16; return x.f;
}
__device__ inline unsigned short f2b(float f) {
  __hip_bfloat16 h = __float2bfloat16(f);
  return *reinterpret_cast<unsigned short*>(&h);
}
__device__ inline void split2(float x, ushort_t& h, ushort_t& l) {
  h = f2b(x);
  l = f2b(x - b2f(h));
}
__device__ inline float geluf(float v) {
  return 0.5f * v * (1.0f + erff(v * 0.70710678118654752f));
}

// ---------------------------------------------------------------------------
// Split-f32 GEMM: C = epi(A[M,K]f32 * B[N,K]f32^T), f32-grade accuracy via
// K-tripled bf16 MFMA: per f32 col c, A' cols [3c..3c+2] = {hi,lo,hi},
// B' = {hi,hi,lo}  =>  sum = hi*hi + lo*hi + hi*lo = a*b - lo*lo (~2^-18 rel).
// EPI: 4 f32 resid += (+bias), 6 f32 store (+z*bC), 7 f32 +bias store,
//      8 f32 *alpha store (+z*bC), 9 f32 gelu(+bias) store.
// ---------------------------------------------------------------------------
template<int EPI>
__global__ __launch_bounds__(256)
void gemm_f32s(const float* __restrict__ A, int lda, long long bA,
               const float* __restrict__ B, int ldb, long long bB,
               float* __restrict__ C, int ldc, long long bC,
               int M, int N, int K,
               const float* __restrict__ bias, float alpha)
{
  int z = blockIdx.z;
  const float* Ap = A + (long long)z * bA;
  const float* Bp = B + (long long)z * bB;
  int m0 = blockIdx.x * 128, n0 = blockIdx.y * 128;

  __shared__ __align__(16) ushort_t As[128 * 104];  // 96 used + 8 pad
  __shared__ __align__(16) ushort_t Bs[128 * 104];

  int tid = threadIdx.x, lane = tid & 63, wave = tid >> 6;
  int wr = (wave >> 1) * 64, wc = (wave & 1) * 64;
  int l15 = lane & 15, l4 = lane >> 4;

  f32x4 acc[4][4];
#pragma unroll
  for (int m = 0; m < 4; ++m)
#pragma unroll
    for (int n = 0; n < 4; ++n) acc[m][n] = (f32x4){0.f, 0.f, 0.f, 0.f};

  for (int k0 = 0; k0 < K; k0 += 32) {
#pragma unroll
    for (int i = 0; i < 4; ++i) {
      int g = tid + i * 256;            // [0,1024)
      int r = g >> 3, c4 = (g & 7) << 2;
      int ra = m0 + r; if (ra > M - 1) ra = M - 1;
      float4 fa = *(const float4*)(Ap + (long long)ra * lda + k0 + c4);
      ushort_t hh, ll;
      ushort_t* da = &As[r * 104 + 3 * c4];
      split2(fa.x, hh, ll); da[0] = hh; da[1]  = ll; da[2]  = hh;
      split2(fa.y, hh, ll); da[3] = hh; da[4]  = ll; da[5]  = hh;
      split2(fa.z, hh, ll); da[6] = hh; da[7]  = ll; da[8]  = hh;
      split2(fa.w, hh, ll); da[9] = hh; da[10] = ll; da[11] = hh;
      int rb = n0 + r; if (rb > N - 1) rb = N - 1;
      float4 fb = *(const float4*)(Bp + (long long)rb * ldb + k0 + c4);
      ushort_t* db = &Bs[r * 104 + 3 * c4];
      split2(fb.x, hh, ll); db[0] = hh; db[1]  = hh; db[2]  = ll;
      split2(fb.y, hh, ll); db[3] = hh; db[4]  = hh; db[5]  = ll;
      split2(fb.z, hh, ll); db[6] = hh; db[7]  = hh; db[8]  = ll;
      split2(fb.w, hh, ll); db[9] = hh; db[10] = hh; db[11] = ll;
    }
    __syncthreads();
#pragma unroll
    for (int kk = 0; kk < 96; kk += 32) {
      bf16x8 af[4], bfr[4];
#pragma unroll
      for (int m = 0; m < 4; ++m)
        af[m] = *(const bf16x8*)&As[(wr + m * 16 + l15) * 104 + kk + l4 * 8];
#pragma unroll
      for (int n = 0; n < 4; ++n)
        bfr[n] = *(const bf16x8*)&Bs[(wc + n * 16 + l15) * 104 + kk + l4 * 8];
#pragma unroll
      for (int m = 0; m < 4; ++m)
#pragma unroll
        for (int n = 0; n < 4; ++n)
          acc[m][n] = __builtin_amdgcn_mfma_f32_16x16x32_bf16(af[m], bfr[n], acc[m][n], 0, 0, 0);
    }
    __syncthreads();
  }

#pragma unroll
  for (int m = 0; m < 4; ++m) {
    int rbase = m0 + wr + m * 16 + l4 * 4;
#pragma unroll
    for (int n = 0; n < 4; ++n) {
      int c = n0 + wc + n * 16 + l15;
      if (c >= N) continue;
      float bv = (EPI == 4 || EPI == 7 || EPI == 9) ? bias[c] : 0.f;
#pragma unroll
      for (int q = 0; q < 4; ++q) {
        int rr = rbase + q;
        if (rr >= M) continue;
        float v = acc[m][n][q];
        long long idx = (long long)rr * ldc + (long long)z * bC + c;
        if (EPI == 4)      C[(long long)rr * ldc + c] += v + bv;
        else if (EPI == 6) C[idx] = v;
        else if (EPI == 7) C[(long long)rr * ldc + c] = v + bv;
        else if (EPI == 8) C[idx] = v * alpha;
        else if (EPI == 9) C[(long long)rr * ldc + c] = geluf(v + bv);
      }
    }
  }
}

// ---------------------------------------------------------------------------
// Plain bf16 GEMM (post-gate paths: MoE experts, head). A bf16 [M,K]; B f32
// weights rounded to bf16 in staging. EPI: 2 gelu(+bias) bf16 store,
// 5 MoE weighted atomic scatter into f32 resid, 6 f32 store.
// ---------------------------------------------------------------------------
template<int EPI>
__global__ __launch_bounds__(256)
void gemm_bt(const ushort_t* __restrict__ A, int lda, long long bA,
             const float* __restrict__ Bv, int ldb, long long bB,
             void* __restrict__ Cv, int ldc, long long bC,
             int M, int N, int K,
             const float* __restrict__ bias, int bBias,
             const int* __restrict__ offs,
             const int* __restrict__ tokIdx, const float* __restrict__ tokW,
             float* __restrict__ xresid)
{
  int z = blockIdx.z;
  const ushort_t* Ap = A + (long long)z * bA;
  int rowStart = 0, Meff = M;
  if (offs) { rowStart = offs[z]; Meff = offs[z + 1] - rowStart; }
  int m0 = blockIdx.x * 128;
  if (m0 >= Meff) return;
  int n0 = blockIdx.y * 128;

  __shared__ __align__(16) ushort_t As[128 * 72];
  __shared__ __align__(16) ushort_t Bs[128 * 72];

  int tid = threadIdx.x, lane = tid & 63, wave = tid >> 6;
  int wr = (wave >> 1) * 64, wc = (wave & 1) * 64;
  int l15 = lane & 15, l4 = lane >> 4;

  f32x4 acc[4][4];
#pragma unroll
  for (int m = 0; m < 4; ++m)
#pragma unroll
    for (int n = 0; n < 4; ++n) acc[m][n] = (f32x4){0.f, 0.f, 0.f, 0.f};

  for (int k0 = 0; k0 < K; k0 += 64) {
#pragma unroll
    for (int i = 0; i < 4; ++i) {
      int g = tid + i * 256;
      int r = g >> 3, ck = (g & 7) << 3;
      int ra = m0 + r; if (ra > Meff - 1) ra = Meff - 1;
      *(s8v*)&As[r * 72 + ck] =
          *(const s8v*)(Ap + (long long)(rowStart + ra) * lda + k0 + ck);
    }
    {
      const float* Bf = Bv + (long long)z * bB;
#pragma unroll
      for (int i = 0; i < 8; ++i) {
        int g = tid + i * 256;
        int r = g >> 4, c4 = (g & 15) * 4;
        int rb = n0 + r; if (rb > N - 1) rb = N - 1;
        float4 f = *(const float4*)(Bf + (long long)rb * ldb + k0 + c4);
        ushort_t* dst = &Bs[r * 72 + c4];
        dst[0] = f2b(f.x); dst[1] = f2b(f.y); dst[2] = f2b(f.z); dst[3] = f2b(f.w);
      }
    }
    __syncthreads();
#pragma unroll
    for (int kk = 0; kk < 64; kk += 32) {
      bf16x8 af[4], bfr[4];
#pragma unroll
      for (int m = 0; m < 4; ++m)
        af[m] = *(const bf16x8*)&As[(wr + m * 16 + l15) * 72 + kk + l4 * 8];
#pragma unroll
      for (int n = 0; n < 4; ++n)
        bfr[n] = *(const bf16x8*)&Bs[(wc + n * 16 + l15) * 72 + kk + l4 * 8];
#pragma unroll
      for (int m = 0; m < 4; ++m)
#pragma unroll
        for (int n = 0; n < 4; ++n)
          acc[m][n] = __builtin_amdgcn_mfma_f32_16x16x32_bf16(af[m], bfr[n], acc[m][n], 0, 0, 0);
    }
    __syncthreads();
  }

#pragma unroll
  for (int m = 0; m < 4; ++m) {
    int rbase = m0 + wr + m * 16 + l4 * 4;
#pragma unroll
    for (int n = 0; n < 4; ++n) {
      int c = n0 + wc + n * 16 + l15;
      if (c >= N) continue;
      float bv = (EPI == 2 || EPI == 5) ? bias[(long long)z * bBias + c] : 0.f;
#pragma unroll
      for (int q = 0; q < 4; ++q) {
        int rr = rbase + q;
        if (rr >= Meff) continue;
        float v = acc[m][n][q];
        long long crow = rowStart + rr;
        if (EPI == 2) {
          ((ushort_t*)Cv)[crow * ldc + (long long)z * bC + c] = f2b(geluf(v + bv));
        } else if (EPI == 5) {
          int t = tokIdx[crow];
          float w = tokW[crow];
          atomicAdd(&xresid[(long long)t * DM + c], w * (v + bv));
        } else if (EPI == 6) {
          ((float*)Cv)[crow * ldc + c] = v;
        }
      }
    }
  }
}

// ---------------------------------------------------------------------------
__global__ __launch_bounds__(256)
void embed_kernel(const int* __restrict__ ids, const float* __restrict__ ew,
                  const float* __restrict__ pw, float* __restrict__ x)
{
  int srow = blockIdx.x, tid = threadIdx.x;
  int id = ids[srow];
  const float4 e = *(const float4*)(ew + (long long)id * DM + tid * 4);
  const float4 p = *(const float4*)(pw + (long long)srow * DM + tid * 4);
  float4* xr = (float4*)(x + (long long)srow * DM) + tid;
  *xr = make_float4(e.x + p.x, e.y + p.y, e.z + p.z, e.w + p.w);
}

template<int BF16OUT>
__global__ __launch_bounds__(256)
void ln_kernel(const float* __restrict__ x, const float* __restrict__ g,
               const float* __restrict__ b, void* __restrict__ out)
{
  int row = blockIdx.x, tid = threadIdx.x;
  float4 v = ((const float4*)(x + (long long)row * DM))[tid];
  __shared__ float sm1[4], sm2[4];
  float s = v.x + v.y + v.z + v.w;
  for (int o = 32; o > 0; o >>= 1) s += __shfl_down(s, o);
  if ((tid & 63) == 0) sm1[tid >> 6] = s;
  __syncthreads();
  float mean = (sm1[0] + sm1[1] + sm1[2] + sm1[3]) * (1.0f / DM);
  float d0 = v.x - mean, d1 = v.y - mean, d2 = v.z - mean, d3 = v.w - mean;
  float q = d0 * d0 + d1 * d1 + d2 * d2 + d3 * d3;
  for (int o = 32; o > 0; o >>= 1) q += __shfl_down(q, o);
  if ((tid & 63) == 0) sm2[tid >> 6] = q;
  __syncthreads();
  float var = (sm2[0] + sm2[1] + sm2[2] + sm2[3]) * (1.0f / DM);
  float rstd = rsqrtf(var + 1e-5f);
  float4 gv = ((const float4*)g)[tid];
  float4 bv = ((const float4*)b)[tid];
  float o0 = d0 * rstd * gv.x + bv.x, o1 = d1 * rstd * gv.y + bv.y;
  float o2 = d2 * rstd * gv.z + bv.z, o3 = d3 * rstd * gv.w + bv.w;
  if (BF16OUT) {
    ushort_t* o4 = (ushort_t*)out + (long long)row * DM + tid * 4;
    o4[0] = f2b(o0); o4[1] = f2b(o1); o4[2] = f2b(o2); o4[3] = f2b(o3);
  } else {
    ((float4*)((float*)out + (long long)row * DM))[tid] = make_float4(o0, o1, o2, o3);
  }
}

__global__ __launch_bounds__(256)
void softmax_rows_f32(float* __restrict__ p)
{
  long long row = blockIdx.x;
  float* pr = p + row * (long long)SQ;
  int tid = threadIdx.x;
  float4 a = ((float4*)pr)[tid * 2], b = ((float4*)pr)[tid * 2 + 1];
  float v[8] = {a.x, a.y, a.z, a.w, b.x, b.y, b.z, b.w};
  float mx = v[0];
#pragma unroll
  for (int i = 1; i < 8; ++i) mx = fmaxf(mx, v[i]);
  for (int o = 32; o > 0; o >>= 1) mx = fmaxf(mx, __shfl_down(mx, o));
  __shared__ float smx[4], ssm[4];
  if ((tid & 63) == 0) smx[tid >> 6] = mx;
  __syncthreads();
  mx = fmaxf(fmaxf(smx[0], smx[1]), fmaxf(smx[2], smx[3]));
  float s = 0.f;
#pragma unroll
  for (int i = 0; i < 8; ++i) { v[i] = expf(v[i] - mx); s += v[i]; }
  for (int o = 32; o > 0; o >>= 1) s += __shfl_down(s, o);
  if ((tid & 63) == 0) ssm[tid >> 6] = s;
  __syncthreads();
  float inv = 1.0f / (ssm[0] + ssm[1] + ssm[2] + ssm[3]);
  ((float4*)pr)[tid * 2]     = make_float4(v[0] * inv, v[1] * inv, v[2] * inv, v[3] * inv);
  ((float4*)pr)[tid * 2 + 1] = make_float4(v[4] * inv, v[5] * inv, v[6] * inv, v[7] * inv);
}

// Vt[h][d][j] = qkv[j][2D + h*64 + d]  (f32)
__global__ __launch_bounds__(256)
void transpose_v_f32(const float* __restrict__ qkv, float* __restrict__ Vt)
{
  __shared__ float t[64][65];
  int j0 = blockIdx.x * 64, h = blockIdx.y;
  int tid = threadIdx.x;
  int jr = tid >> 2, d0 = (tid & 3) * 16;
  const float* src = qkv + (long long)(j0 + jr) * (3 * DM) + 2 * DM + h * 64 + d0;
#pragma unroll
  for (int i = 0; i < 16; ++i) t[jr][d0 + i] = src[i];
  __syncthreads();
  int dd = tid >> 2, jc = (tid & 3) * 16;
  float* dst = Vt + (long long)(h * 64 + dd) * SQ + j0 + jc;
#pragma unroll
  for (int i = 0; i < 16; ++i) dst[i] = t[jc + i][dd];
}

// LN + gate + top2 fully in f32 (routing must track the f32 reference)
__global__ __launch_bounds__(256)
void ln_gate_top2(const float* __restrict__ x, const float* __restrict__ g,
                  const float* __restrict__ b, const float* __restrict__ gw,
                  const float* __restrict__ gb, int* __restrict__ topi,
                  float* __restrict__ topw, int* __restrict__ counts)
{
  int row = blockIdx.x, tid = threadIdx.x;
  float4 v = ((const float4*)(x + (long long)row * DM))[tid];
  __shared__ float sm1[4], sm2[4];
  __shared__ float se[8][4];
  float s = v.x + v.y + v.z + v.w;
  for (int o = 32; o > 0; o >>= 1) s += __shfl_down(s, o);
  if ((tid & 63) == 0) sm1[tid >> 6] = s;
  __syncthreads();
  float mean = (sm1[0] + sm1[1] + sm1[2] + sm1[3]) * (1.0f / DM);
  float d0 = v.x - mean, d1 = v.y - mean, d2 = v.z - mean, d3 = v.w - mean;
  float q = d0 * d0 + d1 * d1 + d2 * d2 + d3 * d3;
  for (int o = 32; o > 0; o >>= 1) q += __shfl_down(q, o);
  if ((tid & 63) == 0) sm2[tid >> 6] = q;
  __syncthreads();
  float var = (sm2[0] + sm2[1] + sm2[2] + sm2[3]) * (1.0f / DM);
  float rstd = rsqrtf(var + 1e-5f);
  float4 gv = ((const float4*)g)[tid];
  float4 bv = ((const float4*)b)[tid];
  float h0 = d0 * rstd * gv.x + bv.x, h1 = d1 * rstd * gv.y + bv.y;
  float h2 = d2 * rstd * gv.z + bv.z, h3 = d3 * rstd * gv.w + bv.w;
#pragma unroll
  for (int e = 0; e < 8; ++e) {
    float4 w = ((const float4*)(gw + (long long)e * DM))[tid];
    float p = h0 * w.x + h1 * w.y + h2 * w.z + h3 * w.w;
    for (int o = 32; o > 0; o >>= 1) p += __shfl_down(p, o);
    if ((tid & 63) == 0) se[e][tid >> 6] = p;
  }
  __syncthreads();
  if (tid == 0) {
    float sc[8];
#pragma unroll
    for (int e = 0; e < 8; ++e)
      sc[e] = se[e][0] + se[e][1] + se[e][2] + se[e][3] + gb[e];
    int i1 = 0; float m1 = sc[0];
    for (int e = 1; e < 8; ++e) if (sc[e] > m1) { m1 = sc[e]; i1 = e; }
    int i2 = -1; float m2 = -1e30f;
    for (int e = 0; e < 8; ++e) if (e != i1 && sc[e] > m2) { m2 = sc[e]; i2 = e; }
    float e2 = expf(m2 - m1);
    float w1 = 1.f / (1.f + e2);
    topi[row * 2] = i1; topi[row * 2 + 1] = i2;
    topw[row * 2] = w1; topw[row * 2 + 1] = 1.f - w1;
    atomicAdd(&counts[i1], 1);
    atomicAdd(&counts[i2], 1);
  }
}

__global__ void moe_zero(int* counts) { if (threadIdx.x < 8) counts[threadIdx.x] = 0; }

__global__ void moe_prefix(const int* __restrict__ counts, int* __restrict__ offs,
                           int* __restrict__ cursors)
{
  if (threadIdx.x == 0 && blockIdx.x == 0) {
    int a = 0;
    for (int e = 0; e < 8; ++e) { offs[e] = a; a += counts[e]; cursors[e] = 0; }
    offs[8] = a;
  }
}

// gather f32 LN output -> bf16 expert-input rows
__global__ __launch_bounds__(256)
void moe_gather(const float* __restrict__ h, const int* __restrict__ topi,
                const float* __restrict__ topw, const int* __restrict__ offs,
                int* __restrict__ cursors, int* __restrict__ tokIdx,
                float* __restrict__ tokW, ushort_t* __restrict__ Xg)
{
  int tok = blockIdx.x, tid = threadIdx.x;
  __shared__ int s0s, s1s;
  if (tid == 0) {
    int e0 = topi[tok * 2], e1 = topi[tok * 2 + 1];
    int s0 = offs[e0] + atomicAdd(&cursors[e0], 1);
    int s1 = offs[e1] + atomicAdd(&cursors[e1], 1);
    tokIdx[s0] = tok; tokW[s0] = topw[tok * 2];
    tokIdx[s1] = tok; tokW[s1] = topw[tok * 2 + 1];
    s0s = s0; s1s = s1;
  }
  __syncthreads();
  float4 v = ((const float4*)(h + (long long)tok * DM))[tid];
  s4v o; o[0] = (short)f2b(v.x); o[1] = (short)f2b(v.y);
  o[2] = (short)f2b(v.z); o[3] = (short)f2b(v.w);
  ((s4v*)(Xg + (long long)s0s * DM))[tid] = o;
  ((s4v*)(Xg + (long long)s1s * DM))[tid] = o;
}

extern "C" void kernel_launch(void* const* d_in, const int* in_sizes, int n_in,
                              void* d_out, int out_size, void* d_ws, size_t ws_size,
                              hipStream_t stream)
{
  const int* ids = (const int*)d_in[0];
  const float* embed_w = (const float*)d_in[1];
  const float* pos_w   = (const float*)d_in[2];
  const float* ln1_g[2] = {(const float*)d_in[3],  (const float*)d_in[11]};
  const float* ln1_b[2] = {(const float*)d_in[4],  (const float*)d_in[12]};
  const float* in_w[2]  = {(const float*)d_in[5],  (const float*)d_in[13]};
  const float* in_b[2]  = {(const float*)d_in[6],  (const float*)d_in[14]};
  const float* out_w[2] = {(const float*)d_in[7],  (const float*)d_in[15]};
  const float* out_b[2] = {(const float*)d_in[8],  (const float*)d_in[16]};
  const float* ln2_g[2] = {(const float*)d_in[9],  (const float*)d_in[17]};
  const float* ln2_b[2] = {(const float*)d_in[10], (const float*)d_in[18]};
  const float* ffn_w1 = (const float*)d_in[19];
  const float* ffn_b1 = (const float*)d_in[20];
  const float* ffn_w2 = (const float*)d_in[21];
  const float* ffn_b2 = (const float*)d_in[22];
  const float* gate_w = (const float*)d_in[23];
  const float* gate_b = (const float*)d_in[24];
  const float* moe_w1 = (const float*)d_in[25];
  const float* moe_b1 = (const float*)d_in[26];
  const float* moe_w2 = (const float*)d_in[27];
  const float* moe_b2 = (const float*)d_in[28];
  const float* norm_g = (const float*)d_in[29];
  const float* norm_b = (const float*)d_in[30];
  const float* head_w = (const float*)d_in[31];

  // Scratch in d_out (262 MB f32; we use ~197 MB; head GEMM overwrites all,
  // reading only hfin (d_ws) + head_w).
  char* ob = (char*)d_out;
  size_t off = 0;
  auto alloc = [&](size_t bytes) {
    char* p = ob + off;
    off = (off + bytes + 255) & ~(size_t)255;
    return p;
  };
  float*    x       = (float*)alloc((size_t)SQ * DM * 4);          //   8 MB
  float*    hbuf    = (float*)alloc((size_t)SQ * DM * 4);          //   8 MB
  float*    qkv     = (float*)alloc((size_t)SQ * 3 * DM * 4);      //  24 MB
  float*    attnout = (float*)alloc((size_t)SQ * DM * 4);          //   8 MB
  float*    Vt      = (float*)alloc((size_t)NH * HDIM * SQ * 4);   // 8.4 MB
  float*    ffnhid  = (float*)alloc((size_t)SQ * FFD * 4);         //  32 MB
  ushort_t* Xg      = (ushort_t*)alloc((size_t)2 * SQ * DM * 2);   //   8 MB
  ushort_t* moehid  = (ushort_t*)alloc((size_t)2 * SQ * FFD * 2);  //  34 MB
  int*      topi    = (int*)alloc(SQ * 2 * 4);
  float*    topw    = (float*)alloc(SQ * 2 * 4);
  int*      tokIdx  = (int*)alloc(2 * SQ * 4);
  float*    tokW    = (float*)alloc(2 * SQ * 4);
  int*      counts  = (int*)alloc(256);
  int*      offsb   = (int*)alloc(256);
  int*      cursors = (int*)alloc(256);
  const int G = 4;
  float*    probs   = (float*)alloc((size_t)G * SQ * SQ * 4);      //  67 MB
  ushort_t* hfin    = (ushort_t*)d_ws;                             //   4 MB

  moe_zero<<<1, 64, 0, stream>>>(counts);
  embed_kernel<<<SQ, 256, 0, stream>>>(ids, embed_w, pos_w, x);

  for (int L = 0; L < 2; ++L) {
    ln_kernel<0><<<SQ, 256, 0, stream>>>(x, ln1_g[L], ln1_b[L], hbuf);
    // qkv = h @ in_w^T + in_b   (f32-grade)
    gemm_f32s<7><<<dim3(16, 24, 1), 256, 0, stream>>>(
        hbuf, DM, 0, in_w[L], DM, 0, qkv, 3 * DM, 0,
        SQ, 3 * DM, DM, in_b[L], 1.f);
    transpose_v_f32<<<dim3(SQ / 64, NH), 256, 0, stream>>>(qkv, Vt);
    for (int h0 = 0; h0 < NH; h0 += G) {
      gemm_f32s<8><<<dim3(16, 16, G), 256, 0, stream>>>(
          qkv + h0 * 64, 3 * DM, 64,
          qkv + DM + h0 * 64, 3 * DM, 64,
          probs, SQ, (long long)SQ * SQ,
          SQ, SQ, 64, nullptr, 0.125f);
      softmax_rows_f32<<<G * SQ, 256, 0, stream>>>(probs);
      gemm_f32s<6><<<dim3(16, 1, G), 256, 0, stream>>>(
          probs, SQ, (long long)SQ * SQ,
          Vt + (long long)h0 * 64 * SQ, SQ, 64LL * SQ,
          attnout + h0 * 64, DM, 64,
          SQ, 64, SQ, nullptr, 1.f);
    }
    // x += attnout @ out_w^T + out_b
    gemm_f32s<4><<<dim3(16, 8, 1), 256, 0, stream>>>(
        attnout, DM, 0, out_w[L], DM, 0, x, DM, 0,
        SQ, DM, DM, out_b[L], 1.f);
    if (L == 0) {
      ln_kernel<0><<<SQ, 256, 0, stream>>>(x, ln2_g[0], ln2_b[0], hbuf);
      gemm_f32s<9><<<dim3(16, 32, 1), 256, 0, stream>>>(
          hbuf, DM, 0, ffn_w1, DM, 0, ffnhid, FFD, 0,
          SQ, FFD, DM, ffn_b1, 1.f);
      gemm_f32s<4><<<dim3(16, 8, 1), 256, 0, stream>>>(
          ffnhid, FFD, 0, ffn_w2, FFD, 0, x, DM, 0,
          SQ, DM, FFD, ffn_b2, 1.f);
    } else {
      ln_gate_top2<<<SQ, 256, 0, stream>>>(x, ln2_g[1], ln2_b[1], gate_w, gate_b,
                                           topi, topw, counts);
      moe_prefix<<<1, 64, 0, stream>>>(counts, offsb, cursors);
      ln_kernel<0><<<SQ, 256, 0, stream>>>(x, ln2_g[1], ln2_b[1], hbuf);
      moe_gather<<<SQ, 256, 0, stream>>>(hbuf, topi, topw, offsb, cursors,
                                         tokIdx, tokW, Xg);
      // per-expert: hid = gelu(Xg @ w1[e]^T + b1[e])   (bf16, post-gate)
      gemm_bt<2><<<dim3(16, 32, 8), 256, 0, stream>>>(
          Xg, DM, 0, moe_w1, DM, (long long)FFD * DM,
          moehid, FFD, 0, SQ, FFD, DM, moe_b1, FFD,
          offsb, nullptr, nullptr, nullptr);
      // x[tok] += w * (hid @ w2[e]^T + b2[e])
      gemm_bt<5><<<dim3(16, 8, 8), 256, 0, stream>>>(
          moehid, FFD, 0, moe_w2, FFD, (long long)DM * FFD,
          nullptr, 0, 0, SQ, DM, FFD, moe_b2, DM,
          offsb, tokIdx, tokW, x);
    }
  }
  // Final LN -> bf16 in d_ws; head GEMM overwrites all of d_out.
  ln_kernel<1><<<SQ, 256, 0, stream>>>(x, norm_g, norm_b, hfin);
  gemm_bt<6><<<dim3(16, 250, 1), 256, 0, stream>>>(
      hfin, DM, 0, head_w, DM, 0, d_out, NVOC, 0,
      SQ, NVOC, DM, nullptr, 0,
      nullptr, nullptr, nullptr, nullptr);
}

// Round 6
// 2104.065 us; speedup vs baseline: 1.4406x; 1.4406x over previous
//
#include <hip/hip_runtime.h>
#include <hip/hip_bf16.h>
#include <math.h>

typedef unsigned short ushort_t;
typedef __attribute__((ext_vector_type(8))) __bf16 bf16x8;
typedef __attribute__((ext_vector_type(4))) float f32x4;
typedef __attribute__((ext_vector_type(8))) short s8v;
typedef __attribute__((ext_vector_type(4))) short s4v;

#define SQ 2048
#define DM 1024
#define NH 16
#define HDIM 64
#define FFD 4096
#define NVOC 32000

__device__ inline float b2f(unsigned short u) {
  union { unsigned int i; float f; } x; x.i = ((unsigned int)u) << 16; return x.f;
}
__device__ inline unsigned short f2b(float f) {
  __hip_bfloat16 h = __float2bfloat16(f);
  return *reinterpret_cast<unsigned short*>(&h);
}
__device__ inline void split2(float x, ushort_t& h, ushort_t& l) {
  h = f2b(x);
  l = f2b(x - b2f(h));
}
__device__ inline float geluf(float v) {
  return 0.5f * v * (1.0f + erff(v * 0.70710678118654752f));
}
// async global->LDS, 16B per lane (m97 pattern; LDS dest = wave base + lane*16)
__device__ __forceinline__ void gld16(const void* g, void* l) {
  __builtin_amdgcn_global_load_lds(
      (const __attribute__((address_space(1))) void*)g,
      (__attribute__((address_space(3))) void*)l, 16, 0, 0);
}

// ---------------------------------------------------------------------------
// Split-f32 GEMM v2: C = epi(A[M,K]f32 * B[N,K]f32^T) with f32-grade accuracy.
// hi/lo bf16 tiles kept SEPARATE in LDS; per 32-f32 K-step, 3 MFMA per (m,n):
// hi*hi + lo*hi + hi*lo  (rel err ~2^-18).
// NT: 128 or 64 (BN). KS: K-split count (z = head*KS + kchunk).
// EPI: 4 f32 resid+=(+bias), 6 f32 store(+h*bC), 7 f32+bias store,
//      8 f32*alpha store(+h*bC), 9 f32 gelu(+bias) store, 10 atomicAdd(+h*bC).
// ---------------------------------------------------------------------------
template<int EPI, int NT, int KS>
__global__ __launch_bounds__(256)
void gemm_f32s(const float* __restrict__ A, int lda, long long bA,
               const float* __restrict__ B, int ldb, long long bB,
               float* __restrict__ C, int ldc, long long bC,
               int M, int N, int K,
               const float* __restrict__ bias, float alpha)
{
  int z = blockIdx.z;
  int h = z / KS, kc = z % KS;
  const float* Ap = A + (long long)h * bA + (long long)kc * K;
  const float* Bp = B + (long long)h * bB + (long long)kc * K;
  int m0 = blockIdx.x * 128, n0 = blockIdx.y * NT;
  const int NF = (NT == 128) ? 4 : 2;

  __shared__ __align__(16) ushort_t Ah[128 * 40], Al[128 * 40];
  __shared__ __align__(16) ushort_t Bh[NT * 40],  Bl[NT * 40];

  int tid = threadIdx.x, lane = tid & 63, wave = tid >> 6;
  int wr = (wave >> 1) * 64, wc = (wave & 1) * (NT >> 1);
  int l15 = lane & 15, l4 = lane >> 4;

  f32x4 acc[4][NF];
#pragma unroll
  for (int m = 0; m < 4; ++m)
#pragma unroll
    for (int n = 0; n < NF; ++n) acc[m][n] = (f32x4){0.f, 0.f, 0.f, 0.f};

  for (int k0 = 0; k0 < K; k0 += 32) {
#pragma unroll
    for (int i = 0; i < 4; ++i) {           // A: 128x32 f32
      int g = tid + i * 256;
      int r = g >> 3, c4 = (g & 7) << 2;
      int ra = m0 + r; if (ra > M - 1) ra = M - 1;
      float4 f = *(const float4*)(Ap + (long long)ra * lda + k0 + c4);
      s4v hv, lv; ushort_t hh, ll;
      split2(f.x, hh, ll); hv[0] = (short)hh; lv[0] = (short)ll;
      split2(f.y, hh, ll); hv[1] = (short)hh; lv[1] = (short)ll;
      split2(f.z, hh, ll); hv[2] = (short)hh; lv[2] = (short)ll;
      split2(f.w, hh, ll); hv[3] = (short)hh; lv[3] = (short)ll;
      *(s4v*)&Ah[r * 40 + c4] = hv;
      *(s4v*)&Al[r * 40 + c4] = lv;
    }
#pragma unroll
    for (int i = 0; i < NT / 32; ++i) {     // B: NTx32 f32
      int g = tid + i * 256;
      int r = g >> 3, c4 = (g & 7) << 2;
      int rb = n0 + r; if (rb > N - 1) rb = N - 1;
      float4 f = *(const float4*)(Bp + (long long)rb * ldb + k0 + c4);
      s4v hv, lv; ushort_t hh, ll;
      split2(f.x, hh, ll); hv[0] = (short)hh; lv[0] = (short)ll;
      split2(f.y, hh, ll); hv[1] = (short)hh; lv[1] = (short)ll;
      split2(f.z, hh, ll); hv[2] = (short)hh; lv[2] = (short)ll;
      split2(f.w, hh, ll); hv[3] = (short)hh; lv[3] = (short)ll;
      *(s4v*)&Bh[r * 40 + c4] = hv;
      *(s4v*)&Bl[r * 40 + c4] = lv;
    }
    __syncthreads();
    bf16x8 ah[4], al[4], bh[NF], bl[NF];
#pragma unroll
    for (int m = 0; m < 4; ++m) {
      ah[m] = *(const bf16x8*)&Ah[(wr + m * 16 + l15) * 40 + l4 * 8];
      al[m] = *(const bf16x8*)&Al[(wr + m * 16 + l15) * 40 + l4 * 8];
    }
#pragma unroll
    for (int n = 0; n < NF; ++n) {
      bh[n] = *(const bf16x8*)&Bh[(wc + n * 16 + l15) * 40 + l4 * 8];
      bl[n] = *(const bf16x8*)&Bl[(wc + n * 16 + l15) * 40 + l4 * 8];
    }
#pragma unroll
    for (int m = 0; m < 4; ++m)
#pragma unroll
      for (int n = 0; n < NF; ++n) {
        acc[m][n] = __builtin_amdgcn_mfma_f32_16x16x32_bf16(ah[m], bh[n], acc[m][n], 0, 0, 0);
        acc[m][n] = __builtin_amdgcn_mfma_f32_16x16x32_bf16(al[m], bh[n], acc[m][n], 0, 0, 0);
        acc[m][n] = __builtin_amdgcn_mfma_f32_16x16x32_bf16(ah[m], bl[n], acc[m][n], 0, 0, 0);
      }
    __syncthreads();
  }

#pragma unroll
  for (int m = 0; m < 4; ++m) {
    int rbase = m0 + wr + m * 16 + l4 * 4;
#pragma unroll
    for (int n = 0; n < NF; ++n) {
      int c = n0 + wc + n * 16 + l15;
      if (c >= N) continue;
      float bv = (EPI == 4 || EPI == 7 || EPI == 9) ? bias[c] : 0.f;
#pragma unroll
      for (int q = 0; q < 4; ++q) {
        int rr = rbase + q;
        if (rr >= M) continue;
        float v = acc[m][n][q];
        if (EPI == 4)       C[(long long)rr * ldc + c] += v + bv;
        else if (EPI == 6)  C[(long long)rr * ldc + (long long)h * bC + c] = v;
        else if (EPI == 7)  C[(long long)rr * ldc + c] = v + bv;
        else if (EPI == 8)  C[(long long)rr * ldc + (long long)h * bC + c] = v * alpha;
        else if (EPI == 9)  C[(long long)rr * ldc + c] = geluf(v + bv);
        else if (EPI == 10) atomicAdd(&C[(long long)rr * ldc + (long long)h * bC + c], v);
      }
    }
  }
}

// ---------------------------------------------------------------------------
// bf16 GEMM (post-gate: MoE experts, head). A bf16 via global_load_lds.
// BSRC=1: B bf16 via global_load_lds. BSRC=0: B f32 reg-staged+rounded.
// EPI: 2 gelu(+bias) bf16 store, 5 MoE weighted atomic scatter, 6 f32 store.
// ---------------------------------------------------------------------------
template<int EPI, int BSRC>
__global__ __launch_bounds__(256)
void gemm_bt(const ushort_t* __restrict__ A, int lda, long long bA,
             const void* __restrict__ Bv, int ldb, long long bB,
             void* __restrict__ Cv, int ldc, long long bC,
             int M, int N, int K,
             const float* __restrict__ bias, int bBias,
             const int* __restrict__ offs,
             const int* __restrict__ tokIdx, const float* __restrict__ tokW,
             float* __restrict__ xresid)
{
  int z = blockIdx.z;
  const ushort_t* Ap = A + (long long)z * bA;
  int rowStart = 0, Meff = M;
  if (offs) { rowStart = offs[z]; Meff = offs[z + 1] - rowStart; }
  int m0 = blockIdx.x * 128;
  if (m0 >= Meff) return;
  int n0 = blockIdx.y * 128;

  __shared__ __align__(16) ushort_t As[128 * 64];
  __shared__ __align__(16) ushort_t Bs[128 * 64];

  int tid = threadIdx.x, lane = tid & 63, wave = tid >> 6;
  int wr = (wave >> 1) * 64, wc = (wave & 1) * 64;
  int l15 = lane & 15, l4 = lane >> 4;

  f32x4 acc[4][4];
#pragma unroll
  for (int m = 0; m < 4; ++m)
#pragma unroll
    for (int n = 0; n < 4; ++n) acc[m][n] = (f32x4){0.f, 0.f, 0.f, 0.f};

  for (int k0 = 0; k0 < K; k0 += 64) {
#pragma unroll
    for (int i = 0; i < 4; ++i) {            // A: 128x64 bf16 direct-to-LDS
      int idx = i * 2048 + tid * 8;
      int row = idx >> 6, col = idx & 63;
      int ra = m0 + row; if (ra > Meff - 1) ra = Meff - 1;
      gld16(Ap + (long long)(rowStart + ra) * lda + k0 + col, &As[idx]);
    }
    if (BSRC == 1) {
      const ushort_t* Bp = (const ushort_t*)Bv + (long long)z * bB;
#pragma unroll
      for (int i = 0; i < 4; ++i) {
        int idx = i * 2048 + tid * 8;
        int row = idx >> 6, col = idx & 63;
        int rb = n0 + row; if (rb > N - 1) rb = N - 1;
        gld16(Bp + (long long)rb * ldb + k0 + col, &Bs[idx]);
      }
    } else {
      const float* Bf = (const float*)Bv + (long long)z * bB;
#pragma unroll
      for (int i = 0; i < 8; ++i) {
        int g = tid + i * 256;
        int r = g >> 4, c4 = (g & 15) * 4;
        int rb = n0 + r; if (rb > N - 1) rb = N - 1;
        float4 f = *(const float4*)(Bf + (long long)rb * ldb + k0 + c4);
        s4v o; o[0] = (short)f2b(f.x); o[1] = (short)f2b(f.y);
        o[2] = (short)f2b(f.z); o[3] = (short)f2b(f.w);
        *(s4v*)&Bs[r * 64 + c4] = o;
      }
    }
    __syncthreads();
#pragma unroll
    for (int kk = 0; kk < 64; kk += 32) {
      bf16x8 af[4], bfr[4];
#pragma unroll
      for (int m = 0; m < 4; ++m)
        af[m] = *(const bf16x8*)&As[(wr + m * 16 + l15) * 64 + kk + l4 * 8];
#pragma unroll
      for (int n = 0; n < 4; ++n)
        bfr[n] = *(const bf16x8*)&Bs[(wc + n * 16 + l15) * 64 + kk + l4 * 8];
#pragma unroll
      for (int m = 0; m < 4; ++m)
#pragma unroll
        for (int n = 0; n < 4; ++n)
          acc[m][n] = __builtin_amdgcn_mfma_f32_16x16x32_bf16(af[m], bfr[n], acc[m][n], 0, 0, 0);
    }
    __syncthreads();
  }

#pragma unroll
  for (int m = 0; m < 4; ++m) {
    int rbase = m0 + wr + m * 16 + l4 * 4;
#pragma unroll
    for (int n = 0; n < 4; ++n) {
      int c = n0 + wc + n * 16 + l15;
      if (c >= N) continue;
      float bv = (EPI == 2 || EPI == 5) ? bias[(long long)z * bBias + c] : 0.f;
#pragma unroll
      for (int q = 0; q < 4; ++q) {
        int rr = rbase + q;
        if (rr >= Meff) continue;
        float v = acc[m][n][q];
        long long crow = rowStart + rr;
        if (EPI == 2) {
          ((ushort_t*)Cv)[crow * ldc + (long long)z * bC + c] = f2b(geluf(v + bv));
        } else if (EPI == 5) {
          int t = tokIdx[crow];
          float w = tokW[crow];
          atomicAdd(&xresid[(long long)t * DM + c], w * (v + bv));
        } else if (EPI == 6) {
          ((float*)Cv)[crow * ldc + c] = v;
        }
      }
    }
  }
}

// ---------------------------------------------------------------------------
__global__ __launch_bounds__(256)
void cvt_bf16(const float* __restrict__ s, ushort_t* __restrict__ d, int n4)
{
  int i = blockIdx.x * blockDim.x + threadIdx.x;
  int stride = gridDim.x * blockDim.x;
  for (; i < n4; i += stride) {
    float4 f = ((const float4*)s)[i];
    s4v o; o[0] = (short)f2b(f.x); o[1] = (short)f2b(f.y);
    o[2] = (short)f2b(f.z); o[3] = (short)f2b(f.w);
    ((s4v*)d)[i] = o;
  }
}

__global__ __launch_bounds__(256)
void embed_kernel(const int* __restrict__ ids, const float* __restrict__ ew,
                  const float* __restrict__ pw, float* __restrict__ x)
{
  int srow = blockIdx.x, tid = threadIdx.x;
  int id = ids[srow];
  const float4 e = *(const float4*)(ew + (long long)id * DM + tid * 4);
  const float4 p = *(const float4*)(pw + (long long)srow * DM + tid * 4);
  float4* xr = (float4*)(x + (long long)srow * DM) + tid;
  *xr = make_float4(e.x + p.x, e.y + p.y, e.z + p.z, e.w + p.w);
}

template<int BF16OUT>
__global__ __launch_bounds__(256)
void ln_kernel(const float* __restrict__ x, const float* __restrict__ g,
               const float* __restrict__ b, void* __restrict__ out)
{
  int row = blockIdx.x, tid = threadIdx.x;
  float4 v = ((const float4*)(x + (long long)row * DM))[tid];
  __shared__ float sm1[4], sm2[4];
  float s = v.x + v.y + v.z + v.w;
  for (int o = 32; o > 0; o >>= 1) s += __shfl_down(s, o);
  if ((tid & 63) == 0) sm1[tid >> 6] = s;
  __syncthreads();
  float mean = (sm1[0] + sm1[1] + sm1[2] + sm1[3]) * (1.0f / DM);
  float d0 = v.x - mean, d1 = v.y - mean, d2 = v.z - mean, d3 = v.w - mean;
  float q = d0 * d0 + d1 * d1 + d2 * d2 + d3 * d3;
  for (int o = 32; o > 0; o >>= 1) q += __shfl_down(q, o);
  if ((tid & 63) == 0) sm2[tid >> 6] = q;
  __syncthreads();
  float var = (sm2[0] + sm2[1] + sm2[2] + sm2[3]) * (1.0f / DM);
  float rstd = rsqrtf(var + 1e-5f);
  float4 gv = ((const float4*)g)[tid];
  float4 bv = ((const float4*)b)[tid];
  float o0 = d0 * rstd * gv.x + bv.x, o1 = d1 * rstd * gv.y + bv.y;
  float o2 = d2 * rstd * gv.z + bv.z, o3 = d3 * rstd * gv.w + bv.w;
  if (BF16OUT) {
    ushort_t* o4 = (ushort_t*)out + (long long)row * DM + tid * 4;
    o4[0] = f2b(o0); o4[1] = f2b(o1); o4[2] = f2b(o2); o4[3] = f2b(o3);
  } else {
    ((float4*)((float*)out + (long long)row * DM))[tid] = make_float4(o0, o1, o2, o3);
  }
}

__global__ __launch_bounds__(256)
void softmax_rows_f32(float* __restrict__ p)
{
  long long row = blockIdx.x;
  float* pr = p + row * (long long)SQ;
  int tid = threadIdx.x;
  float4 a = ((float4*)pr)[tid * 2], b = ((float4*)pr)[tid * 2 + 1];
  float v[8] = {a.x, a.y, a.z, a.w, b.x, b.y, b.z, b.w};
  float mx = v[0];
#pragma unroll
  for (int i = 1; i < 8; ++i) mx = fmaxf(mx, v[i]);
  for (int o = 32; o > 0; o >>= 1) mx = fmaxf(mx, __shfl_down(mx, o));
  __shared__ float smx[4], ssm[4];
  if ((tid & 63) == 0) smx[tid >> 6] = mx;
  __syncthreads();
  mx = fmaxf(fmaxf(smx[0], smx[1]), fmaxf(smx[2], smx[3]));
  float s = 0.f;
#pragma unroll
  for (int i = 0; i < 8; ++i) { v[i] = expf(v[i] - mx); s += v[i]; }
  for (int o = 32; o > 0; o >>= 1) s += __shfl_down(s, o);
  if ((tid & 63) == 0) ssm[tid >> 6] = s;
  __syncthreads();
  float inv = 1.0f / (ssm[0] + ssm[1] + ssm[2] + ssm[3]);
  ((float4*)pr)[tid * 2]     = make_float4(v[0] * inv, v[1] * inv, v[2] * inv, v[3] * inv);
  ((float4*)pr)[tid * 2 + 1] = make_float4(v[4] * inv, v[5] * inv, v[6] * inv, v[7] * inv);
}

__global__ __launch_bounds__(256)
void transpose_v_f32(const float* __restrict__ qkv, float* __restrict__ Vt)
{
  __shared__ float t[64][65];
  int j0 = blockIdx.x * 64, h = blockIdx.y;
  int tid = threadIdx.x;
  int jr = tid >> 2, d0 = (tid & 3) * 16;
  const float* src = qkv + (long long)(j0 + jr) * (3 * DM) + 2 * DM + h * 64 + d0;
#pragma unroll
  for (int i = 0; i < 16; ++i) t[jr][d0 + i] = src[i];
  __syncthreads();
  int dd = tid >> 2, jc = (tid & 3) * 16;
  float* dst = Vt + (long long)(h * 64 + dd) * SQ + j0 + jc;
#pragma unroll
  for (int i = 0; i < 16; ++i) dst[i] = t[jc + i][dd];
}

__global__ __launch_bounds__(256)
void ln_gate_top2(const float* __restrict__ x, const float* __restrict__ g,
                  const float* __restrict__ b, const float* __restrict__ gw,
                  const float* __restrict__ gb, int* __restrict__ topi,
                  float* __restrict__ topw, int* __restrict__ counts)
{
  int row = blockIdx.x, tid = threadIdx.x;
  float4 v = ((const float4*)(x + (long long)row * DM))[tid];
  __shared__ float sm1[4], sm2[4];
  __shared__ float se[8][4];
  float s = v.x + v.y + v.z + v.w;
  for (int o = 32; o > 0; o >>= 1) s += __shfl_down(s, o);
  if ((tid & 63) == 0) sm1[tid >> 6] = s;
  __syncthreads();
  float mean = (sm1[0] + sm1[1] + sm1[2] + sm1[3]) * (1.0f / DM);
  float d0 = v.x - mean, d1 = v.y - mean, d2 = v.z - mean, d3 = v.w - mean;
  float q = d0 * d0 + d1 * d1 + d2 * d2 + d3 * d3;
  for (int o = 32; o > 0; o >>= 1) q += __shfl_down(q, o);
  if ((tid & 63) == 0) sm2[tid >> 6] = q;
  __syncthreads();
  float var = (sm2[0] + sm2[1] + sm2[2] + sm2[3]) * (1.0f / DM);
  float rstd = rsqrtf(var + 1e-5f);
  float4 gv = ((const float4*)g)[tid];
  float4 bv = ((const float4*)b)[tid];
  float h0 = d0 * rstd * gv.x + bv.x, h1 = d1 * rstd * gv.y + bv.y;
  float h2 = d2 * rstd * gv.z + bv.z, h3 = d3 * rstd * gv.w + bv.w;
#pragma unroll
  for (int e = 0; e < 8; ++e) {
    float4 w = ((const float4*)(gw + (long long)e * DM))[tid];
    float p = h0 * w.x + h1 * w.y + h2 * w.z + h3 * w.w;
    for (int o = 32; o > 0; o >>= 1) p += __shfl_down(p, o);
    if ((tid & 63) == 0) se[e][tid >> 6] = p;
  }
  __syncthreads();
  if (tid == 0) {
    float sc[8];
#pragma unroll
    for (int e = 0; e < 8; ++e)
      sc[e] = se[e][0] + se[e][1] + se[e][2] + se[e][3] + gb[e];
    int i1 = 0; float m1 = sc[0];
    for (int e = 1; e < 8; ++e) if (sc[e] > m1) { m1 = sc[e]; i1 = e; }
    int i2 = -1; float m2 = -1e30f;
    for (int e = 0; e < 8; ++e) if (e != i1 && sc[e] > m2) { m2 = sc[e]; i2 = e; }
    float e2 = expf(m2 - m1);
    float w1 = 1.f / (1.f + e2);
    topi[row * 2] = i1; topi[row * 2 + 1] = i2;
    topw[row * 2] = w1; topw[row * 2 + 1] = 1.f - w1;
    atomicAdd(&counts[i1], 1);
    atomicAdd(&counts[i2], 1);
  }
}

__global__ void moe_zero(int* counts) { if (threadIdx.x < 8) counts[threadIdx.x] = 0; }

__global__ void moe_prefix(const int* __restrict__ counts, int* __restrict__ offs,
                           int* __restrict__ cursors)
{
  if (threadIdx.x == 0 && blockIdx.x == 0) {
    int a = 0;
    for (int e = 0; e < 8; ++e) { offs[e] = a; a += counts[e]; cursors[e] = 0; }
    offs[8] = a;
  }
}

__global__ __launch_bounds__(256)
void moe_gather(const float* __restrict__ h, const int* __restrict__ topi,
                const float* __restrict__ topw, const int* __restrict__ offs,
                int* __restrict__ cursors, int* __restrict__ tokIdx,
                float* __restrict__ tokW, ushort_t* __restrict__ Xg)
{
  int tok = blockIdx.x, tid = threadIdx.x;
  __shared__ int s0s, s1s;
  if (tid == 0) {
    int e0 = topi[tok * 2], e1 = topi[tok * 2 + 1];
    int s0 = offs[e0] + atomicAdd(&cursors[e0], 1);
    int s1 = offs[e1] + atomicAdd(&cursors[e1], 1);
    tokIdx[s0] = tok; tokW[s0] = topw[tok * 2];
    tokIdx[s1] = tok; tokW[s1] = topw[tok * 2 + 1];
    s0s = s0; s1s = s1;
  }
  __syncthreads();
  float4 v = ((const float4*)(h + (long long)tok * DM))[tid];
  s4v o; o[0] = (short)f2b(v.x); o[1] = (short)f2b(v.y);
  o[2] = (short)f2b(v.z); o[3] = (short)f2b(v.w);
  ((s4v*)(Xg + (long long)s0s * DM))[tid] = o;
  ((s4v*)(Xg + (long long)s1s * DM))[tid] = o;
}

extern "C" void kernel_launch(void* const* d_in, const int* in_sizes, int n_in,
                              void* d_out, int out_size, void* d_ws, size_t ws_size,
                              hipStream_t stream)
{
  const int* ids = (const int*)d_in[0];
  const float* embed_w = (const float*)d_in[1];
  const float* pos_w   = (const float*)d_in[2];
  const float* ln1_g[2] = {(const float*)d_in[3],  (const float*)d_in[11]};
  const float* ln1_b[2] = {(const float*)d_in[4],  (const float*)d_in[12]};
  const float* in_w[2]  = {(const float*)d_in[5],  (const float*)d_in[13]};
  const float* in_b[2]  = {(const float*)d_in[6],  (const float*)d_in[14]};
  const float* out_w[2] = {(const float*)d_in[7],  (const float*)d_in[15]};
  const float* out_b[2] = {(const float*)d_in[8],  (const float*)d_in[16]};
  const float* ln2_g[2] = {(const float*)d_in[9],  (const float*)d_in[17]};
  const float* ln2_b[2] = {(const float*)d_in[10], (const float*)d_in[18]};
  const float* ffn_w1 = (const float*)d_in[19];
  const float* ffn_b1 = (const float*)d_in[20];
  const float* ffn_w2 = (const float*)d_in[21];
  const float* ffn_b2 = (const float*)d_in[22];
  const float* gate_w = (const float*)d_in[23];
  const float* gate_b = (const float*)d_in[24];
  const float* moe_w1 = (const float*)d_in[25];
  const float* moe_b1 = (const float*)d_in[26];
  const float* moe_w2 = (const float*)d_in[27];
  const float* moe_b2 = (const float*)d_in[28];
  const float* norm_g = (const float*)d_in[29];
  const float* norm_b = (const float*)d_in[30];
  const float* head_w = (const float*)d_in[31];

  // Scratch layout in d_out (250 MiB). Lifetimes:
  //   attention phase: x,hbuf,qkv,attnout,Vt,(ffnhid L0),probs
  //   MoE phase: moe_w1b := probs region (64 MiB exact),
  //              moe_w2b := qkv+attnout+Vt+ffnhid block (72 MiB, dead by then)
  char* ob = (char*)d_out;
  size_t off = 0;
  auto alloc = [&](size_t bytes) {
    char* p = ob + off;
    off = (off + bytes + 255) & ~(size_t)255;
    return p;
  };
  float*    x       = (float*)alloc((size_t)SQ * DM * 4);          //  8 MiB
  float*    hbuf    = (float*)alloc((size_t)SQ * DM * 4);          //  8
  float*    qkv     = (float*)alloc((size_t)SQ * 3 * DM * 4);      // 24  ┐
  float*    attnout = (float*)alloc((size_t)SQ * DM * 4);          //  8  │ w2b
  float*    Vt      = (float*)alloc((size_t)NH * HDIM * SQ * 4);   //  8  │
  float*    ffnhid  = (float*)alloc((size_t)SQ * FFD * 4);         // 32  ┘
  ushort_t* Xg      = (ushort_t*)alloc((size_t)2 * SQ * DM * 2);   //  8
  ushort_t* moehid  = (ushort_t*)alloc((size_t)2 * SQ * FFD * 2);  // 32
  int*      topi    = (int*)alloc(SQ * 2 * 4);
  float*    topw    = (float*)alloc(SQ * 2 * 4);
  int*      tokIdx  = (int*)alloc(2 * SQ * 4);
  float*    tokW    = (float*)alloc(2 * SQ * 4);
  int*      counts  = (int*)alloc(256);
  int*      offsb   = (int*)alloc(256);
  int*      cursors = (int*)alloc(256);
  const int G = 4;
  float*    probs   = (float*)alloc((size_t)G * SQ * SQ * 4);      // 64
  ushort_t* moe_w1b = (ushort_t*)probs;     // 8*4096*1024*2 = 64 MiB exact
  ushort_t* moe_w2b = (ushort_t*)qkv;       // 64 MiB into 72 MiB dead block
  ushort_t* hfin    = (ushort_t*)d_ws;      // 4 MiB
  // head_wb in d_ws if it fits (62.5 MiB + 4 MiB + slack)
  bool wsBig = ws_size >= ((size_t)70 << 20);
  ushort_t* head_wb = (ushort_t*)((char*)d_ws + ((size_t)4 << 20));

  moe_zero<<<1, 64, 0, stream>>>(counts);
  embed_kernel<<<SQ, 256, 0, stream>>>(ids, embed_w, pos_w, x);
  if (wsBig)
    cvt_bf16<<<1024, 256, 0, stream>>>(head_w, head_wb, NVOC * DM / 4);

  for (int L = 0; L < 2; ++L) {
    ln_kernel<0><<<SQ, 256, 0, stream>>>(x, ln1_g[L], ln1_b[L], hbuf);
    // qkv = h @ in_w^T + in_b   (f32-grade)
    gemm_f32s<7, 128, 1><<<dim3(16, 24, 1), 256, 0, stream>>>(
        hbuf, DM, 0, in_w[L], DM, 0, qkv, 3 * DM, 0,
        SQ, 3 * DM, DM, in_b[L], 1.f);
    transpose_v_f32<<<dim3(SQ / 64, NH), 256, 0, stream>>>(qkv, Vt);
    hipMemsetAsync(attnout, 0, (size_t)SQ * DM * 4, stream);
    for (int h0 = 0; h0 < NH; h0 += G) {
      gemm_f32s<8, 128, 1><<<dim3(16, 16, G), 256, 0, stream>>>(
          qkv + h0 * 64, 3 * DM, 64,
          qkv + DM + h0 * 64, 3 * DM, 64,
          probs, SQ, (long long)SQ * SQ,
          SQ, SQ, 64, nullptr, 0.125f);
      softmax_rows_f32<<<G * SQ, 256, 0, stream>>>(probs);
      // PV: NT=64, 4-way K-split, atomicAdd epilogue -> 256 blocks
      gemm_f32s<10, 64, 4><<<dim3(16, 1, G * 4), 256, 0, stream>>>(
          probs, SQ, (long long)SQ * SQ,
          Vt + (long long)h0 * 64 * SQ, SQ, 64LL * SQ,
          attnout + h0 * 64, DM, 64,
          SQ, 64, SQ / 4, nullptr, 1.f);
    }
    // x += attnout @ out_w^T + out_b  (NT=64 -> 256 blocks)
    gemm_f32s<4, 64, 1><<<dim3(16, 16, 1), 256, 0, stream>>>(
        attnout, DM, 0, out_w[L], DM, 0, x, DM, 0,
        SQ, DM, DM, out_b[L], 1.f);
    if (L == 0) {
      ln_kernel<0><<<SQ, 256, 0, stream>>>(x, ln2_g[0], ln2_b[0], hbuf);
      gemm_f32s<9, 128, 1><<<dim3(16, 32, 1), 256, 0, stream>>>(
          hbuf, DM, 0, ffn_w1, DM, 0, ffnhid, FFD, 0,
          SQ, FFD, DM, ffn_b1, 1.f);
      gemm_f32s<4, 64, 1><<<dim3(16, 16, 1), 256, 0, stream>>>(
          ffnhid, FFD, 0, ffn_w2, FFD, 0, x, DM, 0,
          SQ, DM, FFD, ffn_b2, 1.f);
    } else {
      // qkv/attnout/Vt/ffnhid and probs are dead now -> convert MoE weights
      cvt_bf16<<<1024, 256, 0, stream>>>(moe_w1, moe_w1b, 8 * FFD * DM / 4);
      cvt_bf16<<<1024, 256, 0, stream>>>(moe_w2, moe_w2b, 8 * DM * FFD / 4);
      ln_gate_top2<<<SQ, 256, 0, stream>>>(x, ln2_g[1], ln2_b[1], gate_w, gate_b,
                                           topi, topw, counts);
      moe_prefix<<<1, 64, 0, stream>>>(counts, offsb, cursors);
      ln_kernel<0><<<SQ, 256, 0, stream>>>(x, ln2_g[1], ln2_b[1], hbuf);
      moe_gather<<<SQ, 256, 0, stream>>>(hbuf, topi, topw, offsb, cursors,
                                         tokIdx, tokW, Xg);
      gemm_bt<2, 1><<<dim3(16, 32, 8), 256, 0, stream>>>(
          Xg, DM, 0, moe_w1b, DM, (long long)FFD * DM,
          moehid, FFD, 0, SQ, FFD, DM, moe_b1, FFD,
          offsb, nullptr, nullptr, nullptr);
      gemm_bt<5, 1><<<dim3(16, 8, 8), 256, 0, stream>>>(
          moehid, FFD, 0, moe_w2b, FFD, (long long)DM * FFD,
          nullptr, 0, 0, SQ, DM, FFD, moe_b2, DM,
          offsb, tokIdx, tokW, x);
    }
  }
  ln_kernel<1><<<SQ, 256, 0, stream>>>(x, norm_g, norm_b, hfin);
  if (wsBig) {
    gemm_bt<6, 1><<<dim3(16, 250, 1), 256, 0, stream>>>(
        hfin, DM, 0, head_wb, DM, 0, d_out, NVOC, 0,
        SQ, NVOC, DM, nullptr, 0,
        nullptr, nullptr, nullptr, nullptr);
  } else {
    gemm_bt<6, 0><<<dim3(16, 250, 1), 256, 0, stream>>>(
        hfin, DM, 0, head_w, DM, 0, d_out, NVOC, 0,
        SQ, NVOC, DM, nullptr, 0,
        nullptr, nullptr, nullptr, nullptr);
  }
}